// Round 6
// baseline (43.460 us; speedup 1.0000x reference)
//
#include <hip/hip_runtime.h>
#include <hip/hip_bf16.h>
#include <stdint.h>

// Chamfer distance, B=2, N=M=8192, fp32 3-D points — MFMA, two transposed passes.
//
// d2[n][m] = |p_n|^2 + |g_m|^2 - 2 p_n.g_m inside v_mfma_f32_32x32x16_bf16 via
// split-bf16 (hi+lo), K=16 (encoding + A/B/C layouts verified R3-R5: absmax 0.0):
//   A_k: [-2hx,-2hy,-2hz, -2hx,-2hy,-2hz, -2lx,-2ly,-2lz, -2lx,-2ly,-2lz, h2,l2,1,1]
//   B_k: [ hx, hy, hz,  lx, ly, lz,  hx, hy, hz,  lx, ly, lz,  1,1, h2,l2]
// Two passes (dir 0/1, A/B swapped); only row-mins, folded in-register.
//
// R6 vs R5 (41.4us, regression) / R4 (30.5us):
//  - R5's 128-col double-buffer had ~100cyc compute between barriers (2-phase
//    stall regime, m233). Now: stage the WHOLE 1024-col chunk (32KB LDS) with
//    ONE barrier, then 16 unrolled steps of {2 ds_read imm-offset, 4 MFMA,
//    32 v_min3} — no per-step addressing, no more barriers.
//  - 2x2 register blocking (2 row-frags x 2 col-tiles): 0.5 ds_read/MFMA
//    -> DS pipe 2.6us/CU < MFMA 3.4us/CU (at 1/MFMA DS would dominate, 5.1us).
//  - A-encode inlined before the barrier (overlaps stage latency).

typedef __attribute__((ext_vector_type(8))) short short8v;
typedef __attribute__((ext_vector_type(16))) float f32x16;

#define NP 8192
#define NCHUNK 8
#define CHUNKCOLS 1024
#define ROWS_PER_BLOCK 256       // 4 waves x 64 rows
#define SCALE 0.390625f          // 80^2 / (2 * 8192)

// ws byte offsets
#define OFF_ROW 0u         // float[4 db][8 chunk][8192]   row-min partials (1 MB)
#define OFF_B   4194304u   // uint4[4 db][2 half][8192]    B k-half planes (4 MB)

__device__ inline uint32_t f2u(float f){ union{float f;uint32_t u;}c; c.f=f; return c.u; }
__device__ inline float u2f(uint32_t u){ union{float f;uint32_t u;}c; c.u=u; return c.f; }
__device__ inline uint16_t bfr(float f){ uint32_t u=f2u(f); return (uint16_t)((u + 0x7FFFu + ((u>>16)&1u))>>16); }
__device__ inline float bff(uint16_t s){ return u2f(((uint32_t)s)<<16); }
__device__ inline float min3f(float a,float b,float c){ return fminf(fminf(a,b),c); }

__device__ inline short8v encodeA(float x, float y, float z, int half) {
  const uint16_t hx=bfr(x), hy=bfr(y), hz=bfr(z);
  const uint16_t lx=bfr(x-bff(hx)), ly=bfr(y-bff(hy)), lz=bfr(z-bff(hz));
  const float s2 = fmaf(x,x,fmaf(y,y,z*z));
  const uint16_t h2=bfr(s2), l2=bfr(s2-bff(h2));
  const uint16_t nhx=bfr(-2.f*bff(hx)), nhy=bfr(-2.f*bff(hy)), nhz=bfr(-2.f*bff(hz));
  const uint16_t nlx=bfr(-2.f*bff(lx)), nly=bfr(-2.f*bff(ly)), nlz=bfr(-2.f*bff(lz));
  union{ ushort u[16]; short8v s8[2]; } A;
  A.u[0]=nhx; A.u[1]=nhy; A.u[2]=nhz; A.u[3]=nhx; A.u[4]=nhy; A.u[5]=nhz;
  A.u[6]=nlx; A.u[7]=nly; A.u[8]=nlz; A.u[9]=nlx; A.u[10]=nly; A.u[11]=nlz;
  A.u[12]=h2; A.u[13]=l2; A.u[14]=0x3F80; A.u[15]=0x3F80;
  return half ? A.s8[1] : A.s8[0];
}

// ---------------- prep: pack B k-half planes ----------------
__global__ __launch_bounds__(256) void prep_kernel(
    const float* __restrict__ pred, const float* __restrict__ gt,
    float* __restrict__ out, uint8_t* __restrict__ ws) {
  const int tid = blockIdx.x*256 + (int)threadIdx.x;   // 0..65535
  if (tid == 0) out[0] = 0.0f;
  const int col  = tid & 8191;
  const int half = (tid >> 13) & 1;
  const int db   = tid >> 14;          // dir*2 + b
  const int dir = db >> 1, b = db & 1;

  const float* src = (dir == 0 ? gt : pred) + ((size_t)b*NP + col)*3;
  const float x = src[0], y = src[1], z = src[2];

  const uint16_t hx=bfr(x), hy=bfr(y), hz=bfr(z);
  const uint16_t lx=bfr(x-bff(hx)), ly=bfr(y-bff(hy)), lz=bfr(z-bff(hz));
  const float s2 = fmaf(x,x,fmaf(y,y,z*z));
  const uint16_t h2=bfr(s2), l2=bfr(s2-bff(h2));
  union{ ushort u[16]; uint4 v[2]; } B;
  B.u[0]=hx; B.u[1]=hy; B.u[2]=hz; B.u[3]=lx; B.u[4]=ly; B.u[5]=lz;
  B.u[6]=hx; B.u[7]=hy; B.u[8]=hz; B.u[9]=lx; B.u[10]=ly; B.u[11]=lz;
  B.u[12]=0x3F80; B.u[13]=0x3F80; B.u[14]=h2; B.u[15]=l2;

  uint4* BP = (uint4*)(ws + OFF_B);
  BP[(size_t)tid] = half ? B.v[1] : B.v[0];   // [(db*2+half)*NP + col]
}

// ---------------- main MFMA kernel ----------------
__global__ __launch_bounds__(256) void chamfer_mfma_kernel(
    const float* __restrict__ pred, const float* __restrict__ gt,
    uint8_t* __restrict__ ws) {
  const int wave = threadIdx.x >> 6, lane = threadIdx.x & 63;
  const int half = lane >> 5, l31 = lane & 31;
  const int rowblk = blockIdx.x;            // 0..31
  const int chunk  = blockIdx.y;            // 0..7
  const int db     = blockIdx.z;            // dir*2 + b
  const int dir = db >> 1, b = db & 1;

  __shared__ uint4 ldsB[2][CHUNKCOLS];      // 32 KB, single-buffered

  // ---- stage the whole chunk (both k-half planes), 8 uint4 per thread
  const uint4* BP = (const uint4*)(ws + OFF_B) + (size_t)db*2*NP
                    + (size_t)chunk*CHUNKCOLS;
#pragma unroll
  for (int k = 0; k < 8; ++k) {
    const int gidx = k*256 + (int)threadIdx.x;   // 0..2047
    const int h = gidx >> 10, c = gidx & 1023;
    ((uint4*)ldsB)[gidx] = BP[(size_t)h*NP + c];
  }

  // ---- inline A-encode for the wave's 2 row-fragments (overlaps staging)
  const float* abase = (dir == 0 ? pred : gt) + (size_t)b*NP*3;
  const int row0 = rowblk*ROWS_PER_BLOCK + wave*64 + l31;  // and row0+32
  short8v afrag0, afrag1;
  {
    const float* a0 = abase + (size_t)row0*3;
    afrag0 = encodeA(a0[0], a0[1], a0[2], half);
    const float* a1 = abase + (size_t)(row0+32)*3;
    afrag1 = encodeA(a1[0], a1[1], a1[2], half);
  }

  float rm0[16], rm1[16];
#pragma unroll
  for (int i=0;i<16;++i) { rm0[i] = 3.4e38f; rm1[i] = 3.4e38f; }
  const f32x16 zero = {};

  __syncthreads();

  // ---- 16 steps x {2 ds_read_b128 (imm offset), 4 MFMA, 32 v_min3}
  const uint4* lb = &ldsB[half][l31];
#pragma unroll
  for (int t = 0; t < 32; t += 2) {
    const short8v b0 = *(const short8v*)(lb + t*32);
    const short8v b1 = *(const short8v*)(lb + t*32 + 32);
    const f32x16 m00 = __builtin_amdgcn_mfma_f32_32x32x16_bf16(afrag0, b0, zero, 0,0,0);
    const f32x16 m01 = __builtin_amdgcn_mfma_f32_32x32x16_bf16(afrag0, b1, zero, 0,0,0);
    const f32x16 m10 = __builtin_amdgcn_mfma_f32_32x32x16_bf16(afrag1, b0, zero, 0,0,0);
    const f32x16 m11 = __builtin_amdgcn_mfma_f32_32x32x16_bf16(afrag1, b1, zero, 0,0,0);
#pragma unroll
    for (int i=0;i<16;++i) {
      rm0[i] = min3f(rm0[i], m00[i], m01[i]);
      rm1[i] = min3f(rm1[i], m10[i], m11[i]);
    }
  }

  // ---- row-min across the 32 cols (lanes) per half
#pragma unroll
  for (int i=0;i<16;++i) {
    float v0 = rm0[i], v1 = rm1[i];
    v0 = fminf(v0, __shfl_xor(v0, 1));  v1 = fminf(v1, __shfl_xor(v1, 1));
    v0 = fminf(v0, __shfl_xor(v0, 2));  v1 = fminf(v1, __shfl_xor(v1, 2));
    v0 = fminf(v0, __shfl_xor(v0, 4));  v1 = fminf(v1, __shfl_xor(v1, 4));
    v0 = fminf(v0, __shfl_xor(v0, 8));  v1 = fminf(v1, __shfl_xor(v1, 8));
    v0 = fminf(v0, __shfl_xor(v0, 16)); v1 = fminf(v1, __shfl_xor(v1, 16));
    rm0[i] = v0; rm1[i] = v1;
  }
  if (l31 == 0) {
    // C/D map (verified): row = (i&3) + 8*(i>>2) + 4*half
    float* wr = (float*)(ws + OFF_ROW) + ((size_t)db*NCHUNK + chunk)*NP
                + rowblk*ROWS_PER_BLOCK + wave*64 + half*4;
#pragma unroll
    for (int i=0;i<16;++i) {
      const int r = (i&3) + 8*(i>>2);
      wr[r] = rm0[i];
      wr[r + 32] = rm1[i];
    }
  }
}

// ---------------- final reduce ----------------
__global__ __launch_bounds__(256) void reduce_kernel(
    const uint8_t* __restrict__ ws, float* __restrict__ out) {
  const float* WROW = (const float*)(ws + OFF_ROW);
  const int tid = blockIdx.x*256 + (int)threadIdx.x;  // 0..32767
  const int db = tid >> 13, q = tid & 8191;

  const float* pr = WROW + (size_t)db*NCHUNK*NP + q;
  float mn = 3.4e38f;
#pragma unroll
  for (int k = 0; k < NCHUNK; ++k) mn = fminf(mn, pr[(size_t)k*NP]);
  float sum = fmaxf(mn, 0.0f);  // clamp == ref's maximum(d2,0)

#pragma unroll
  for (int off=32; off>0; off>>=1) sum += __shfl_down(sum, off);
  __shared__ float red[4];
  if ((threadIdx.x & 63) == 0) red[threadIdx.x >> 6] = sum;
  __syncthreads();
  if (threadIdx.x == 0) atomicAdd(out, (red[0]+red[1]+red[2]+red[3]) * SCALE);
}

extern "C" void kernel_launch(void* const* d_in, const int* in_sizes, int n_in,
                              void* d_out, int out_size, void* d_ws, size_t ws_size,
                              hipStream_t stream) {
  const float* pred = (const float*)d_in[0];
  const float* gt = (const float*)d_in[1];
  float* out = (float*)d_out;
  uint8_t* ws = (uint8_t*)d_ws;

  prep_kernel<<<256, 256, 0, stream>>>(pred, gt, out, ws);
  chamfer_mfma_kernel<<<dim3(NP/ROWS_PER_BLOCK, NCHUNK, 4), 256, 0, stream>>>(pred, gt, ws);
  reduce_kernel<<<128, 256, 0, stream>>>(ws, out);
}

// Round 7
// 42.108 us; speedup vs baseline: 1.0321x; 1.0321x over previous
//
#include <hip/hip_runtime.h>
#include <hip/hip_bf16.h>
#include <stdint.h>

// Chamfer distance, B=2, N=M=8192, fp32 3-D points — MFMA, two transposed passes.
//
// d2[n][m] = |p_n|^2 + |g_m|^2 - 2 p_n.g_m inside v_mfma_f32_32x32x16_bf16 via
// split-bf16 (hi+lo), K=16 (encoding + A/B/C layouts verified R3-R6: absmax 0.0):
//   A_k: [-2hx,-2hy,-2hz, -2hx,-2hy,-2hz, -2lx,-2ly,-2lz, -2lx,-2ly,-2lz, h2,l2,1,1]
//   B_k: [ hx, hy, hz,  lx, ly, lz,  hx, hy, hz,  lx, ly, lz,  1,1, h2,l2]
// Two passes (dir 0/1, A/B swapped); only row-mins, folded in-register.
//
// R7 vs R6 (43.5us): ONE change — the 16-step inner loop is a runtime loop
// with #pragma unroll 2 instead of fully unrolled. Theory: full unroll let the
// scheduler hoist loads/MFMAs across all 16 bodies -> liveness explosion ->
// scratch spills (invisible in correctness, 5x-class slowdown). unroll 2 caps
// the window (~100 live VGPRs), matching R4's pressure profile while keeping
// R6's LDS-fed, barrier-free loop. Clean A/B on register pressure alone.

typedef __attribute__((ext_vector_type(8))) short short8v;
typedef __attribute__((ext_vector_type(16))) float f32x16;

#define NP 8192
#define NCHUNK 8
#define CHUNKCOLS 1024
#define ROWS_PER_BLOCK 256       // 4 waves x 64 rows
#define SCALE 0.390625f          // 80^2 / (2 * 8192)

// ws byte offsets
#define OFF_ROW 0u         // float[4 db][8 chunk][8192]   row-min partials (1 MB)
#define OFF_B   4194304u   // uint4[4 db][2 half][8192]    B k-half planes (4 MB)

__device__ inline uint32_t f2u(float f){ union{float f;uint32_t u;}c; c.f=f; return c.u; }
__device__ inline float u2f(uint32_t u){ union{float f;uint32_t u;}c; c.u=u; return c.f; }
__device__ inline uint16_t bfr(float f){ uint32_t u=f2u(f); return (uint16_t)((u + 0x7FFFu + ((u>>16)&1u))>>16); }
__device__ inline float bff(uint16_t s){ return u2f(((uint32_t)s)<<16); }
__device__ inline float min3f(float a,float b,float c){ return fminf(fminf(a,b),c); }

__device__ inline short8v encodeA(float x, float y, float z, int half) {
  const uint16_t hx=bfr(x), hy=bfr(y), hz=bfr(z);
  const uint16_t lx=bfr(x-bff(hx)), ly=bfr(y-bff(hy)), lz=bfr(z-bff(hz));
  const float s2 = fmaf(x,x,fmaf(y,y,z*z));
  const uint16_t h2=bfr(s2), l2=bfr(s2-bff(h2));
  const uint16_t nhx=bfr(-2.f*bff(hx)), nhy=bfr(-2.f*bff(hy)), nhz=bfr(-2.f*bff(hz));
  const uint16_t nlx=bfr(-2.f*bff(lx)), nly=bfr(-2.f*bff(ly)), nlz=bfr(-2.f*bff(lz));
  union{ ushort u[16]; short8v s8[2]; } A;
  A.u[0]=nhx; A.u[1]=nhy; A.u[2]=nhz; A.u[3]=nhx; A.u[4]=nhy; A.u[5]=nhz;
  A.u[6]=nlx; A.u[7]=nly; A.u[8]=nlz; A.u[9]=nlx; A.u[10]=nly; A.u[11]=nlz;
  A.u[12]=h2; A.u[13]=l2; A.u[14]=0x3F80; A.u[15]=0x3F80;
  return half ? A.s8[1] : A.s8[0];
}

// ---------------- prep: pack B k-half planes ----------------
__global__ __launch_bounds__(256) void prep_kernel(
    const float* __restrict__ pred, const float* __restrict__ gt,
    float* __restrict__ out, uint8_t* __restrict__ ws) {
  const int tid = blockIdx.x*256 + (int)threadIdx.x;   // 0..65535
  if (tid == 0) out[0] = 0.0f;
  const int col  = tid & 8191;
  const int half = (tid >> 13) & 1;
  const int db   = tid >> 14;          // dir*2 + b
  const int dir = db >> 1, b = db & 1;

  const float* src = (dir == 0 ? gt : pred) + ((size_t)b*NP + col)*3;
  const float x = src[0], y = src[1], z = src[2];

  const uint16_t hx=bfr(x), hy=bfr(y), hz=bfr(z);
  const uint16_t lx=bfr(x-bff(hx)), ly=bfr(y-bff(hy)), lz=bfr(z-bff(hz));
  const float s2 = fmaf(x,x,fmaf(y,y,z*z));
  const uint16_t h2=bfr(s2), l2=bfr(s2-bff(h2));
  union{ ushort u[16]; uint4 v[2]; } B;
  B.u[0]=hx; B.u[1]=hy; B.u[2]=hz; B.u[3]=lx; B.u[4]=ly; B.u[5]=lz;
  B.u[6]=hx; B.u[7]=hy; B.u[8]=hz; B.u[9]=lx; B.u[10]=ly; B.u[11]=lz;
  B.u[12]=0x3F80; B.u[13]=0x3F80; B.u[14]=h2; B.u[15]=l2;

  uint4* BP = (uint4*)(ws + OFF_B);
  BP[(size_t)tid] = half ? B.v[1] : B.v[0];   // [(db*2+half)*NP + col]
}

// ---------------- main MFMA kernel ----------------
__global__ __launch_bounds__(256) void chamfer_mfma_kernel(
    const float* __restrict__ pred, const float* __restrict__ gt,
    uint8_t* __restrict__ ws) {
  const int wave = threadIdx.x >> 6, lane = threadIdx.x & 63;
  const int half = lane >> 5, l31 = lane & 31;
  const int rowblk = blockIdx.x;            // 0..31
  const int chunk  = blockIdx.y;            // 0..7
  const int db     = blockIdx.z;            // dir*2 + b
  const int dir = db >> 1, b = db & 1;

  __shared__ uint4 ldsB[2][CHUNKCOLS];      // 32 KB, single-buffered

  // ---- stage the whole chunk (both k-half planes), 8 uint4 per thread
  const uint4* BP = (const uint4*)(ws + OFF_B) + (size_t)db*2*NP
                    + (size_t)chunk*CHUNKCOLS;
#pragma unroll
  for (int k = 0; k < 8; ++k) {
    const int gidx = k*256 + (int)threadIdx.x;   // 0..2047
    const int h = gidx >> 10, c = gidx & 1023;
    ((uint4*)ldsB)[gidx] = BP[(size_t)h*NP + c];
  }

  // ---- inline A-encode for the wave's 2 row-fragments (overlaps staging)
  const float* abase = (dir == 0 ? pred : gt) + (size_t)b*NP*3;
  const int row0 = rowblk*ROWS_PER_BLOCK + wave*64 + l31;  // and row0+32
  short8v afrag0, afrag1;
  {
    const float* a0 = abase + (size_t)row0*3;
    afrag0 = encodeA(a0[0], a0[1], a0[2], half);
    const float* a1 = abase + (size_t)(row0+32)*3;
    afrag1 = encodeA(a1[0], a1[1], a1[2], half);
  }

  float rm0[16], rm1[16];
#pragma unroll
  for (int i=0;i<16;++i) { rm0[i] = 3.4e38f; rm1[i] = 3.4e38f; }
  const f32x16 zero = {};

  __syncthreads();

  // ---- 16 steps x {2 ds_read_b128, 4 MFMA, 32 v_min3}; runtime loop,
  // unroll 2 to cap liveness (R7's single change vs R6's full unroll).
  const uint4* lb = &ldsB[half][l31];
#pragma unroll 2
  for (int t = 0; t < 32; t += 2) {
    const short8v b0 = *(const short8v*)(lb + t*32);
    const short8v b1 = *(const short8v*)(lb + t*32 + 32);
    const f32x16 m00 = __builtin_amdgcn_mfma_f32_32x32x16_bf16(afrag0, b0, zero, 0,0,0);
    const f32x16 m01 = __builtin_amdgcn_mfma_f32_32x32x16_bf16(afrag0, b1, zero, 0,0,0);
    const f32x16 m10 = __builtin_amdgcn_mfma_f32_32x32x16_bf16(afrag1, b0, zero, 0,0,0);
    const f32x16 m11 = __builtin_amdgcn_mfma_f32_32x32x16_bf16(afrag1, b1, zero, 0,0,0);
#pragma unroll
    for (int i=0;i<16;++i) {
      rm0[i] = min3f(rm0[i], m00[i], m01[i]);
      rm1[i] = min3f(rm1[i], m10[i], m11[i]);
    }
  }

  // ---- row-min across the 32 cols (lanes) per half
#pragma unroll
  for (int i=0;i<16;++i) {
    float v0 = rm0[i], v1 = rm1[i];
    v0 = fminf(v0, __shfl_xor(v0, 1));  v1 = fminf(v1, __shfl_xor(v1, 1));
    v0 = fminf(v0, __shfl_xor(v0, 2));  v1 = fminf(v1, __shfl_xor(v1, 2));
    v0 = fminf(v0, __shfl_xor(v0, 4));  v1 = fminf(v1, __shfl_xor(v1, 4));
    v0 = fminf(v0, __shfl_xor(v0, 8));  v1 = fminf(v1, __shfl_xor(v1, 8));
    v0 = fminf(v0, __shfl_xor(v0, 16)); v1 = fminf(v1, __shfl_xor(v1, 16));
    rm0[i] = v0; rm1[i] = v1;
  }
  if (l31 == 0) {
    // C/D map (verified): row = (i&3) + 8*(i>>2) + 4*half
    float* wr = (float*)(ws + OFF_ROW) + ((size_t)db*NCHUNK + chunk)*NP
                + rowblk*ROWS_PER_BLOCK + wave*64 + half*4;
#pragma unroll
    for (int i=0;i<16;++i) {
      const int r = (i&3) + 8*(i>>2);
      wr[r] = rm0[i];
      wr[r + 32] = rm1[i];
    }
  }
}

// ---------------- final reduce ----------------
__global__ __launch_bounds__(256) void reduce_kernel(
    const uint8_t* __restrict__ ws, float* __restrict__ out) {
  const float* WROW = (const float*)(ws + OFF_ROW);
  const int tid = blockIdx.x*256 + (int)threadIdx.x;  // 0..32767
  const int db = tid >> 13, q = tid & 8191;

  const float* pr = WROW + (size_t)db*NCHUNK*NP + q;
  float mn = 3.4e38f;
#pragma unroll
  for (int k = 0; k < NCHUNK; ++k) mn = fminf(mn, pr[(size_t)k*NP]);
  float sum = fmaxf(mn, 0.0f);  // clamp == ref's maximum(d2,0)

#pragma unroll
  for (int off=32; off>0; off>>=1) sum += __shfl_down(sum, off);
  __shared__ float red[4];
  if ((threadIdx.x & 63) == 0) red[threadIdx.x >> 6] = sum;
  __syncthreads();
  if (threadIdx.x == 0) atomicAdd(out, (red[0]+red[1]+red[2]+red[3]) * SCALE);
}

extern "C" void kernel_launch(void* const* d_in, const int* in_sizes, int n_in,
                              void* d_out, int out_size, void* d_ws, size_t ws_size,
                              hipStream_t stream) {
  const float* pred = (const float*)d_in[0];
  const float* gt = (const float*)d_in[1];
  float* out = (float*)d_out;
  uint8_t* ws = (uint8_t*)d_ws;

  prep_kernel<<<256, 256, 0, stream>>>(pred, gt, out, ws);
  chamfer_mfma_kernel<<<dim3(NP/ROWS_PER_BLOCK, NCHUNK, 4), 256, 0, stream>>>(pred, gt, ws);
  reduce_kernel<<<128, 256, 0, stream>>>(ws, out);
}